// Round 3
// baseline (5504.261 us; speedup 1.0000x reference)
//
#include <hip/hip_runtime.h>
#include <hip/hip_bf16.h>
#include <cstdint>

typedef __attribute__((ext_vector_type(4))) float f32x4;
typedef __attribute__((ext_vector_type(8))) short s16x8;
typedef __hip_bfloat16 bf;

#define BDIM 256

// ---------------------------------------------------------------------------
// Generic bf16 MFMA gemm (used for batched pre/post work only):
// out[M,N] = act( A[M,K] @ W[N,:]^T + bias[N] ), W row-major with stride ldw.
// ---------------------------------------------------------------------------
struct GemmP {
    const bf* A1;
    const bf* A2;
    const bf* W;
    const float* bias;
    float* outF;
    bf* outB;
};

template <int BM, int BN, int ACT, bool OUTB>
__global__ __launch_bounds__(BDIM) void gemm_k(GemmP p0, GemmP p1, int K1, int K2, int ldw,
                                               int M, int N) {
    constexpr int LDT = 40;  // shorts per LDS row: 32 + 8 pad
    __shared__ short lA[BM * LDT];
    __shared__ short lW[BN * LDT];
    const GemmP p = (blockIdx.z == 0) ? p0 : p1;
    const int K = K1 + K2;
    const int bm = blockIdx.x * BM;
    const int bn = blockIdx.y * BN;
    const int tid = threadIdx.x;
    const int lane = tid & 63;
    const int wid = tid >> 6;
    constexpr int WM = BM / 2, WN = BN / 2;
    constexpr int TM = WM / 16, TN = WN / 16;
    const int wm = (wid >> 1) * WM;
    const int wn = (wid & 1) * WN;
    const int q = lane >> 4, l16 = lane & 15;
    (void)M;

    f32x4 acc[TM][TN] = {};

    for (int k0 = 0; k0 < K; k0 += 32) {
        for (int c = tid; c < BM * 4; c += BDIM) {
            int row = c >> 2, kc = c & 3;
            int k = k0 + kc * 8;
            const bf* src;
            if (k < K1) src = p.A1 + (size_t)(bm + row) * K1 + k;
            else        src = p.A2 + (size_t)(bm + row) * K2 + (k - K1);
            *(s16x8*)(lA + row * LDT + kc * 8) = *(const s16x8*)src;
        }
        for (int c = tid; c < BN * 4; c += BDIM) {
            int row = c >> 2, kc = c & 3;
            int k = k0 + kc * 8;
            *(s16x8*)(lW + row * LDT + kc * 8) =
                *(const s16x8*)(p.W + (size_t)(bn + row) * ldw + k);
        }
        __syncthreads();

        s16x8 af[TM], wf[TN];
#pragma unroll
        for (int i = 0; i < TM; i++)
            af[i] = *(const s16x8*)(lA + (wm + i * 16 + l16) * LDT + q * 8);
#pragma unroll
        for (int j = 0; j < TN; j++)
            wf[j] = *(const s16x8*)(lW + (wn + j * 16 + l16) * LDT + q * 8);
#pragma unroll
        for (int i = 0; i < TM; i++)
#pragma unroll
            for (int j = 0; j < TN; j++)
                acc[i][j] = __builtin_amdgcn_mfma_f32_16x16x32_bf16(af[i], wf[j], acc[i][j], 0, 0, 0);
        __syncthreads();
    }

#pragma unroll
    for (int i = 0; i < TM; i++)
#pragma unroll
        for (int j = 0; j < TN; j++)
#pragma unroll
            for (int r = 0; r < 4; r++) {
                int row = bm + wm + i * 16 + q * 4 + r;
                int col = bn + wn + j * 16 + l16;
                float v = acc[i][j][r] + p.bias[col];
                if (ACT == 1) v = v > 0.0f ? v : expm1f(v);
                if (OUTB) p.outB[(size_t)row * N + col] = __float2bfloat16(v);
                else      p.outF[(size_t)row * N + col] = v;
            }
}

// ---------------------------------------------------------------------------
// Persistent-scan GEMM tile: BK=64 K-steps, LDS-staged, 3-buffer register
// prefetch ring, XOR-swizzled LDS (conflict-free b128 read+write, proven r2).
// ---------------------------------------------------------------------------
template <int BM, int BN, int WR, int WC>
__device__ __forceinline__ void gemm_tile(
    const bf* __restrict__ A1, int lda1, int K1,
    const bf* __restrict__ A2, int lda2, int K2,
    const bf* __restrict__ W, int ldw, int wrow0, int gstride,
    int arow0, short* lA, short* lW,
    f32x4 (&acc)[BM / (16 * WR)][BN / (16 * WC)]) {
    constexpr int TM = BM / (16 * WR), TN = BN / (16 * WC);
    constexpr int ACH = (BM * 8) / BDIM;
    constexpr int WCH = (BN * 8 + BDIM - 1) / BDIM;
    constexpr bool WFULL = (BN * 8) % BDIM == 0;
    const int tid = threadIdx.x;
    const int lane = tid & 63, wid = tid >> 6;
    const int wm = (wid / WC) * (BM / WR);
    const int wn = (wid % WC) * (BN / WC);
    const int q = lane >> 4, l16 = lane & 15;
    const int K = K1 + K2;
    const int niter = (K + 63) >> 6;

    s16x8 raA[ACH], rwA[WCH], raB[ACH], rwB[WCH], raC[ACH], rwC[WCH];

    auto issue = [&](s16x8 (&ra)[ACH], s16x8 (&rw)[WCH], int it2) {
        const int k0 = it2 << 6;
#pragma unroll
        for (int u = 0; u < ACH; u++) {
            const int c = tid + u * BDIM;
            const int row = c >> 3, kc = c & 7;
            const int k = k0 + kc * 8;
            s16x8 v = {};
            if (k < K1)     v = *(const s16x8*)(A1 + (size_t)(arow0 + row) * lda1 + k);
            else if (k < K) v = *(const s16x8*)(A2 + (size_t)(arow0 + row) * lda2 + (k - K1));
            ra[u] = v;
        }
#pragma unroll
        for (int u = 0; u < WCH; u++) {
            const int c = tid + u * BDIM;
            if (WFULL || c < BN * 8) {
                const int row = c >> 3, kc = c & 7;
                const int wrr = wrow0 + (row >> 4) * gstride + (row & 15);
                const int k = k0 + kc * 8;
                s16x8 v = {};
                if (k < K) v = *(const s16x8*)(W + (size_t)wrr * ldw + k);
                rw[u] = v;
            }
        }
    };
    auto commit = [&](const s16x8 (&ra)[ACH], const s16x8 (&rw)[WCH]) {
#pragma unroll
        for (int u = 0; u < ACH; u++) {
            const int c = tid + u * BDIM;
            const int row = c >> 3, kc = c & 7;
            *(s16x8*)(lA + row * 64 + ((kc ^ (row & 7)) << 3)) = ra[u];
        }
#pragma unroll
        for (int u = 0; u < WCH; u++) {
            const int c = tid + u * BDIM;
            if (WFULL || c < BN * 8) {
                const int row = c >> 3, kc = c & 7;
                *(s16x8*)(lW + row * 64 + ((kc ^ (row & 7)) << 3)) = rw[u];
            }
        }
    };
    auto compute = [&]() {
#pragma unroll
        for (int kk = 0; kk < 2; kk++) {
            const int ch = kk * 4 + q;
            s16x8 af[TM], wf[TN];
#pragma unroll
            for (int i = 0; i < TM; i++) {
                const int r = wm + i * 16 + l16;
                af[i] = *(const s16x8*)(lA + r * 64 + ((ch ^ (r & 7)) << 3));
            }
#pragma unroll
            for (int j = 0; j < TN; j++) {
                const int r = wn + j * 16 + l16;
                wf[j] = *(const s16x8*)(lW + r * 64 + ((ch ^ (r & 7)) << 3));
            }
#pragma unroll
            for (int i = 0; i < TM; i++)
#pragma unroll
                for (int j = 0; j < TN; j++)
                    acc[i][j] = __builtin_amdgcn_mfma_f32_16x16x32_bf16(af[i], wf[j], acc[i][j], 0, 0, 0);
        }
    };

    issue(raA, rwA, 0);
    issue(raB, rwB, 1);
    int it = 0;
    while (true) {
        __syncthreads();
        commit(raA, rwA);
        if (it + 2 < niter) issue(raC, rwC, it + 2);
        __syncthreads();
        compute();
        if (++it >= niter) break;
        __syncthreads();
        commit(raB, rwB);
        if (it + 2 < niter) issue(raA, rwA, it + 2);
        __syncthreads();
        compute();
        if (++it >= niter) break;
        __syncthreads();
        commit(raC, rwC);
        if (it + 2 < niter) issue(raB, rwB, it + 2);
        __syncthreads();
        compute();
        if (++it >= niter) break;
    }
}

// ---------------------------------------------------------------------------
// Decentralized per-block signal flags (monotone), SUBSET waits: each wait
// polls only the arithmetically-known producer set (8..64 blocks) with a
// single wave. No RMW serialization (r1 flaw), no 256x256 poll storm (r2
// flaw). Producer targets differ per class: blocks <64 ("Q") vs >=64 ("W").
// ---------------------------------------------------------------------------
template <typename PF>
__device__ __forceinline__ void waitf(unsigned* flags, int n, PF pidf,
                                      unsigned tq, unsigned tw) {
    const int tid = threadIdx.x;
    if (tid < n) {
        const int p = pidf(tid);
        const unsigned tgt = (p < 64) ? tq : tw;
        while (__hip_atomic_load(flags + p * 32, __ATOMIC_RELAXED, __HIP_MEMORY_SCOPE_AGENT) < tgt)
            __builtin_amdgcn_s_sleep(2);
    }
    __syncthreads();
    __builtin_amdgcn_fence(__ATOMIC_ACQUIRE, "agent");
}

__device__ __forceinline__ void sigf(unsigned* flags, int blk, unsigned val) {
    __syncthreads();
    __builtin_amdgcn_fence(__ATOMIC_RELEASE, "agent");
    if (threadIdx.x == 0)
        __hip_atomic_store(flags + blk * 32, val, __ATOMIC_RELAXED, __HIP_MEMORY_SCOPE_AGENT);
}

// ---------------------------------------------------------------------------
// Persistent scan kernel. Per iteration t:
//   all: wait E_x(t)[16] -> gi(t) GEMM -> wait E_gh(t)[48, overlapped] -> h(t)
//   W  : wait E_h(t)[64] -> gh(t+1)
//   Q  : wait E_h(t)[64] -> hq(t); Q0: wait E_hq(t)[16] -> mq(t)+s(t+1);
//        Q: wait E_s(t)[8] -> x(t+1)
// Signals/iter: Q +4, W +2. Flag at x(t)=1+4t (Q), gh(t)=1+2t (W).
// ---------------------------------------------------------------------------
struct ScanP {
    const bf *Wsa, *Wih, *Whh, *Wpoh, *Wpos;
    const float *b_sa, *b_ih, *b_hh, *b_pos;
    const bf* act;           // [T,256,32] bf16
    const float* obsW;       // [T*256,1024] fp32: obs@Wpoh_obs^T + b_poh
    bf *x_b, *h_b, *hq_b, *s_b, *hs_b;
    float* gh;               // [256,3072] fp32 scratch
    const float *prev_belief, *nonterm, *eps_q;
    float *o_bel, *o_pos, *o_pom, *o_posd;
    unsigned* flags;
};

__global__ __launch_bounds__(BDIM, 1) void scan_k(ScanP P) {
    __shared__ short lA[64 * 64];
    __shared__ short lW[64 * 64];
    const int blk = blockIdx.x;
    const int tid = threadIdx.x;
    const int lane = tid & 63, wid = tid >> 6;
    const int q = lane >> 4, l16 = lane & 15;
    unsigned* F = P.flags;
    const bool isW = blk >= 64;
    const int mg = (blk >> 3) & 3;          // own A-row group for gi/hq/x (0..3)
    const int mh = ((blk - 64) >> 3) & 3;   // A-row group for gh (W only)

    // ---- XCD-aware tile maps (blk->XCD assumed blk&7) ----
    const int xcd = blk & 7;
    const int s2 = blk >> 3;
    const int c0g = (xcd * 8 + (s2 >> 2)) * 16;    // gi col group (all 256)
    const int bmg = mg * 64;
    const int u_w = blk - 64;
    const int s_w = u_w >> 3;
    const int bn_h = ((u_w & 7) * 6 + (s_w >> 2)) * 64;   // gh (blocks 64..255)
    const int bm_h = (s_w & 3) * 64;
    const int s3 = blk >> 3;                       // hq/x (blocks 0..63)
    const int bn_q = (xcd * 2 + (s3 >> 2)) * 64;
    const int bm_q = (s3 & 3) * 64;
    const int c0m = xcd * 16;                      // mq (blocks 0..31)
    const int bm_m = (blk >> 3) * 64;

    auto do_gh = [&]() {
        const int wm = (wid >> 1) * 32, wn = (wid & 1) * 32;
        f32x4 acc[2][2];
#pragma unroll
        for (int i = 0; i < 2; i++)
#pragma unroll
            for (int j = 0; j < 2; j++) {
                const float b = P.b_hh[bn_h + wn + j * 16 + l16];
                acc[i][j] = (f32x4){b, b, b, b};
            }
        gemm_tile<64, 64, 2, 2>(P.h_b, 1024, 1024, nullptr, 0, 0,
                                P.Whh, 1024, bn_h, 16, bm_h, lA, lW, acc);
#pragma unroll
        for (int i = 0; i < 2; i++)
#pragma unroll
            for (int j = 0; j < 2; j++)
#pragma unroll
                for (int r = 0; r < 4; r++)
                    P.gh[(size_t)(bm_h + wm + i * 16 + q * 4 + r) * 3072
                         + bn_h + wn + j * 16 + l16] = acc[i][j][r];
    };

    auto do_x = [&](int tt) {
        const int wm = (wid >> 1) * 32, wn = (wid & 1) * 32;
        f32x4 acc[2][2];
#pragma unroll
        for (int i = 0; i < 2; i++)
#pragma unroll
            for (int j = 0; j < 2; j++) {
                const float b = P.b_sa[bn_q + wn + j * 16 + l16];
                acc[i][j] = (f32x4){b, b, b, b};
            }
        gemm_tile<64, 64, 2, 2>(P.s_b, 128, 128, P.act + (size_t)tt * 256 * 32, 32, 32,
                                P.Wsa, 160, bn_q, 16, bm_q, lA, lW, acc);
#pragma unroll
        for (int i = 0; i < 2; i++)
#pragma unroll
            for (int j = 0; j < 2; j++)
#pragma unroll
                for (int r = 0; r < 4; r++) {
                    float v = acc[i][j][r];
                    v = v > 0.f ? v : expm1f(v);
                    P.x_b[(size_t)(bm_q + wm + i * 16 + q * 4 + r) * 1024
                          + bn_q + wn + j * 16 + l16] = __float2bfloat16(v);
                }
    };

    auto do_hq = [&](f32x4 (&acc)[2][2]) {
        const int wm = (wid >> 1) * 32, wn = (wid & 1) * 32;
        gemm_tile<64, 64, 2, 2>(P.h_b, 1024, 1024, nullptr, 0, 0,
                                P.Wpoh, 2048, bn_q, 16, bm_q, lA, lW, acc);
#pragma unroll
        for (int i = 0; i < 2; i++)
#pragma unroll
            for (int j = 0; j < 2; j++)
#pragma unroll
                for (int r = 0; r < 4; r++) {
                    float v = acc[i][j][r];
                    v = v > 0.f ? v : expm1f(v);
                    P.hq_b[(size_t)(bm_q + wm + i * 16 + q * 4 + r) * 1024
                           + bn_q + wn + j * 16 + l16] = __float2bfloat16(v);
                }
    };

    auto do_mq = [&](int tt) {
        f32x4 acc[1][2];
#pragma unroll
        for (int j = 0; j < 2; j++) {
            const float b = P.b_pos[j * 128 + c0m + l16];
            acc[0][j] = (f32x4){b, b, b, b};
        }
        gemm_tile<64, 32, 4, 1>(P.hq_b, 1024, 1024, nullptr, 0, 0,
                                P.Wpos, 1024, c0m, 128, bm_m, lA, lW, acc);
        const float* nt1 = (tt + 1 < 50) ? (P.nonterm + (size_t)(tt + 1) * 256) : nullptr;
#pragma unroll
        for (int r = 0; r < 4; r++) {
            const int row = bm_m + wid * 16 + q * 4 + r;
            const int col = c0m + l16;
            const size_t oi = (size_t)tt * 32768 + (size_t)row * 128 + col;
            const float m = acc[0][0][r], sraw = acc[0][1][r];
            const float s = (sraw > 20.f ? sraw : log1pf(expf(sraw))) + 0.1f;
            const float st = m + s * P.eps_q[oi];
            P.o_pom[oi] = m;
            P.o_posd[oi] = s;
            P.o_pos[oi] = st;
            if (nt1) P.s_b[(size_t)row * 128 + col] = __float2bfloat16(st * nt1[row]);
        }
    };

    // ---- prologue: x(0) || gh(0) ----
    if (isW) { do_gh(); sigf(F, blk, 1); }
    else     { do_x(0); sigf(F, blk, 1); }

    for (int t = 0; t < 50; t++) {
        const unsigned q0 = 1 + 4u * (unsigned)t, w0 = 1 + 2u * (unsigned)t;

        // ---- gi(t): GEMM needs x rows bmg (16 Q producers); epilogue needs
        //      gh rows bmg (48 W producers, wait overlapped by the GEMM) ----
        {
            f32x4 acc[1][3];
#pragma unroll
            for (int g = 0; g < 3; g++) {
                const float b = P.b_ih[g * 1024 + c0g + l16];
                acc[0][g] = (f32x4){b, b, b, b};
            }
            waitf(F, 16, [&](int i) { return ((i >> 3) << 5) | (mg << 3) | (i & 7); }, q0, 0u);
            gemm_tile<64, 48, 4, 1>(P.x_b, 1024, 1024, nullptr, 0, 0,
                                    P.Wih, 1024, c0g, 1024, bmg, lA, lW, acc);
            waitf(F, 48, [&](int i) { return 64 + (((i >> 3) << 5) | (mg << 3) | (i & 7)); }, 0u, w0);
            const float* bel = (t == 0) ? P.prev_belief : (P.o_bel + (size_t)(t - 1) * 262144);
#pragma unroll
            for (int r = 0; r < 4; r++) {
                const int row = bmg + wid * 16 + q * 4 + r;
                const int col = c0g + l16;
                const size_t o3 = (size_t)row * 3072 + col;
                const float gir = acc[0][0][r] + P.gh[o3];
                const float giz = acc[0][1][r] + P.gh[o3 + 1024];
                const float rr = 1.f / (1.f + expf(-gir));
                const float zz = 1.f / (1.f + expf(-giz));
                const float nn = tanhf(acc[0][2][r] + rr * P.gh[o3 + 2048]);
                const size_t oo = (size_t)row * 1024 + col;
                const float h = (1.f - zz) * nn + zz * bel[oo];
                P.o_bel[(size_t)t * 262144 + oo] = h;
                const bf hb = __float2bfloat16(h);
                P.h_b[oo] = hb;
                P.hs_b[(size_t)t * 262144 + oo] = hb;
            }
        }
        sigf(F, blk, isW ? w0 + 1 : q0 + 1);

        if (isW) {
            if (t == 49) break;
            // gh(t+1) needs h rows bm_h (64 producers, mixed class)
            waitf(F, 64, [&](int i) { return ((i >> 3) << 5) | (mh << 3) | (i & 7); },
                  q0 + 1, w0 + 1);
            do_gh();
            sigf(F, blk, w0 + 2);
        } else {
            // preload obsW C-init before the wait (latency hides under spin)
            f32x4 qa[2][2];
            const int wm = (wid >> 1) * 32, wn = (wid & 1) * 32;
#pragma unroll
            for (int i = 0; i < 2; i++)
#pragma unroll
                for (int j = 0; j < 2; j++)
#pragma unroll
                    for (int r = 0; r < 4; r++)
                        qa[i][j][r] = P.obsW[(size_t)(t * 256 + bm_q + wm + i * 16 + q * 4 + r) * 1024
                                             + bn_q + wn + j * 16 + l16];
            // hq(t) needs h rows bm_q (64 producers, mixed class)
            waitf(F, 64, [&](int i) { return ((i >> 3) << 5) | (mg << 3) | (i & 7); },
                  q0 + 1, w0 + 1);
            do_hq(qa);
            sigf(F, blk, blk < 32 ? q0 + 2 : q0 + 3);
            if (blk < 32) {
                // mq(t) needs hq rows bm_m (16 Q producers)
                waitf(F, 16, [&](int i) { return ((i >> 3) << 5) | (mg << 3) | (i & 7); },
                      q0 + 2, 0u);
                do_mq(t);
                sigf(F, blk, q0 + 3);
            }
            if (t == 49) break;
            // x(t+1) needs s rows bm_q (8 Q0 producers)
            waitf(F, 8, [&](int i) { return (mg << 3) | i; }, q0 + 3, 0u);
            do_x(t + 1);
            sigf(F, blk, q0 + 4);
        }
    }
}

// ---------------------------------------------------------------------------
// Head pointwise for batched prior outputs.
// ---------------------------------------------------------------------------
__global__ __launch_bounds__(BDIM) void head_pw(const float* __restrict__ msq, const float* __restrict__ eps,
                                                float* __restrict__ o_st, float* __restrict__ o_mu,
                                                float* __restrict__ o_sd, int total) {
    int idx = blockIdx.x * BDIM + threadIdx.x;
    if (idx >= total) return;
    int b = idx >> 7, j = idx & 127;
    float m = msq[(size_t)b * 256 + j];
    float sraw = msq[(size_t)b * 256 + 128 + j];
    float s = (sraw > 20.0f ? sraw : log1pf(expf(sraw))) + 0.1f;
    o_mu[idx] = m;
    o_sd[idx] = s;
    o_st[idx] = m + s * eps[idx];
}

// ---------------------------------------------------------------------------
// Init: s_b = bf16(prev_state * nt[0]), h_b = bf16(prev_belief), zero flags.
// ---------------------------------------------------------------------------
__global__ __launch_bounds__(BDIM) void init_k(const float* __restrict__ prev_state,
                                               const float* __restrict__ nt0,
                                               const float* __restrict__ prev_belief,
                                               bf* __restrict__ s_b,
                                               bf* __restrict__ bel_b,
                                               unsigned* __restrict__ flags) {
    int idx = blockIdx.x * BDIM + threadIdx.x;
    if (idx < 256 * 1024) bel_b[idx] = __float2bfloat16(prev_belief[idx]);
    if (idx < 256 * 128) {
        int b = idx >> 7;
        s_b[idx] = __float2bfloat16(prev_state[idx] * nt0[b]);
    }
    if (idx < 256 * 32) flags[idx] = 0u;
}

// ---------------------------------------------------------------------------
// fp32 -> bf16 conversion of 9 arrays in one launch
// ---------------------------------------------------------------------------
struct ConvP {
    const float* src[9];
    bf* dst[9];
    int n4[9];
};

__global__ __launch_bounds__(BDIM) void conv_k(ConvP cp) {
    int stride = gridDim.x * BDIM;
    int g = blockIdx.x * BDIM + threadIdx.x;
    for (int s = 0; s < 9; s++) {
        const float4* src = (const float4*)cp.src[s];
        unsigned short* dst = (unsigned short*)cp.dst[s];
        int n4 = cp.n4[s];
        for (int i = g; i < n4; i += stride) {
            float4 v = src[i];
            bf h0 = __float2bfloat16(v.x), h1 = __float2bfloat16(v.y);
            bf h2 = __float2bfloat16(v.z), h3 = __float2bfloat16(v.w);
            ushort4 o;
            o.x = *(unsigned short*)&h0;
            o.y = *(unsigned short*)&h1;
            o.z = *(unsigned short*)&h2;
            o.w = *(unsigned short*)&h3;
            *(ushort4*)(dst + (size_t)4 * i) = o;
        }
    }
}

// ---------------------------------------------------------------------------
extern "C" void kernel_launch(void* const* d_in, const int* in_sizes, int n_in,
                              void* d_out, int out_size, void* d_ws, size_t ws_size,
                              hipStream_t stream) {
    constexpr int B = 256, T = 50;
    constexpr int BELIEF = 1024, STATE = 128, ACTION = 32, HIDDEN = 1024, EMBED = 1024;

    const float* prev_state  = (const float*)d_in[0];
    const float* actions     = (const float*)d_in[1];
    const float* prev_belief = (const float*)d_in[2];
    const float* observ      = (const float*)d_in[3];
    const float* nonterm     = (const float*)d_in[4];
    const float* eps_p       = (const float*)d_in[5];
    const float* eps_q       = (const float*)d_in[6];
    const float* W_sa  = (const float*)d_in[7];
    const float* b_sa  = (const float*)d_in[8];
    const float* W_ih  = (const float*)d_in[9];
    const float* b_ih  = (const float*)d_in[10];
    const float* W_hh  = (const float*)d_in[11];
    const float* b_hh  = (const float*)d_in[12];
    const float* W_prh = (const float*)d_in[13];
    const float* b_prh = (const float*)d_in[14];
    const float* W_prs = (const float*)d_in[15];
    const float* b_prs = (const float*)d_in[16];
    const float* W_poh = (const float*)d_in[17];
    const float* b_poh = (const float*)d_in[18];
    const float* W_pos = (const float*)d_in[19];
    const float* b_pos = (const float*)d_in[20];
    float* out = (float*)d_out;

    // ---- workspace carve ----
    char* wsp = (char*)d_ws;
    size_t off = 0;
    auto alloc = [&](size_t bytes) -> void* {
        void* p = wsp + off;
        off = (off + bytes + 255) & ~(size_t)255;
        return p;
    };
    bf* Wsa_b  = (bf*)alloc((size_t)BELIEF * (STATE + ACTION) * 2);
    bf* Wih_b  = (bf*)alloc((size_t)3 * BELIEF * BELIEF * 2);
    bf* Whh_b  = (bf*)alloc((size_t)3 * BELIEF * BELIEF * 2);
    bf* Wprh_b = (bf*)alloc((size_t)HIDDEN * BELIEF * 2);
    bf* Wprs_b = (bf*)alloc((size_t)2 * STATE * HIDDEN * 2);
    bf* Wpoh_b = (bf*)alloc((size_t)HIDDEN * (BELIEF + EMBED) * 2);
    bf* Wpos_b = (bf*)alloc((size_t)2 * STATE * HIDDEN * 2);
    bf* act_b  = (bf*)alloc((size_t)T * B * ACTION * 2);
    bf* s_b    = (bf*)alloc((size_t)B * STATE * 2);
    bf* x_b    = (bf*)alloc((size_t)B * BELIEF * 2);
    bf* h_b    = (bf*)alloc((size_t)B * BELIEF * 2);
    bf* hq_b   = (bf*)alloc((size_t)B * HIDDEN * 2);
    bf* hs_b   = (bf*)alloc((size_t)T * B * BELIEF * 2);
    float* gh_ws = (float*)alloc((size_t)B * 3 * BELIEF * 4);
    unsigned* flags = (unsigned*)alloc(256 * 32 * 4);
    bf* obs_b  = (bf*)alloc((size_t)T * B * EMBED * 2);            // dead after obsW gemm
    float* obsW = (float*)alloc((size_t)T * B * HIDDEN * 4);       // dead after scan
    bf* hp_b    = obs_b;                                           // post-scan alias
    float* mpsp = obsW;                                            // post-scan alias
    (void)ws_size; (void)in_sizes; (void)n_in; (void)out_size;

    // ---- output layout ----
    const size_t BEL = (size_t)T * B * BELIEF;
    const size_t SML = (size_t)T * B * STATE;
    float* o_bel  = out;
    float* o_prs  = out + BEL;
    float* o_prm  = o_prs + SML;
    float* o_prsd = o_prm + SML;
    float* o_pos  = o_prsd + SML;
    float* o_pom  = o_pos + SML;
    float* o_posd = o_pom + SML;

    // ---- one-time conversions ----
    ConvP cp;
    cp.src[0] = W_sa;   cp.dst[0] = Wsa_b;  cp.n4[0] = BELIEF * (STATE + ACTION) / 4;
    cp.src[1] = W_ih;   cp.dst[1] = Wih_b;  cp.n4[1] = 3 * BELIEF * BELIEF / 4;
    cp.src[2] = W_hh;   cp.dst[2] = Whh_b;  cp.n4[2] = 3 * BELIEF * BELIEF / 4;
    cp.src[3] = W_prh;  cp.dst[3] = Wprh_b; cp.n4[3] = HIDDEN * BELIEF / 4;
    cp.src[4] = W_prs;  cp.dst[4] = Wprs_b; cp.n4[4] = 2 * STATE * HIDDEN / 4;
    cp.src[5] = W_poh;  cp.dst[5] = Wpoh_b; cp.n4[5] = HIDDEN * (BELIEF + EMBED) / 4;
    cp.src[6] = W_pos;  cp.dst[6] = Wpos_b; cp.n4[6] = 2 * STATE * HIDDEN / 4;
    cp.src[7] = actions; cp.dst[7] = act_b; cp.n4[7] = T * B * ACTION / 4;
    cp.src[8] = observ;  cp.dst[8] = obs_b; cp.n4[8] = T * B * EMBED / 4;
    conv_k<<<2048, BDIM, 0, stream>>>(cp);
    init_k<<<(B * BELIEF) / BDIM, BDIM, 0, stream>>>(prev_state, nonterm, prev_belief, s_b, h_b, flags);

    // ---- precompute obsW[t] = obs_t @ Wpoh_obs^T + b_poh (batched over T) ----
    {
        GemmP p{obs_b, nullptr, Wpoh_b + EMBED, b_poh, obsW, nullptr};
        gemm_k<128, 64, 0, false><<<dim3(T * B / 128, HIDDEN / 64, 1), BDIM, 0, stream>>>(
            p, p, EMBED, 0, BELIEF + EMBED, T * B, HIDDEN);
    }

    // ---- persistent scan: all 50 timesteps in one kernel ----
    {
        ScanP SP;
        SP.Wsa = Wsa_b; SP.Wih = Wih_b; SP.Whh = Whh_b; SP.Wpoh = Wpoh_b; SP.Wpos = Wpos_b;
        SP.b_sa = b_sa; SP.b_ih = b_ih; SP.b_hh = b_hh; SP.b_pos = b_pos;
        SP.act = act_b; SP.obsW = obsW;
        SP.x_b = x_b; SP.h_b = h_b; SP.hq_b = hq_b; SP.s_b = s_b; SP.hs_b = hs_b;
        SP.gh = gh_ws;
        SP.prev_belief = prev_belief; SP.nonterm = nonterm; SP.eps_q = eps_q;
        SP.o_bel = o_bel; SP.o_pos = o_pos; SP.o_pom = o_pom; SP.o_posd = o_posd;
        SP.flags = flags;
        scan_k<<<256, BDIM, 0, stream>>>(SP);
    }

    // ---- prior head, batched over all T (off the critical path) ----
    {
        GemmP p{hs_b, nullptr, Wprh_b, b_prh, nullptr, hp_b};
        gemm_k<128, 64, 1, true><<<dim3(T * B / 128, HIDDEN / 64, 1), BDIM, 0, stream>>>(
            p, p, BELIEF, 0, BELIEF, T * B, HIDDEN);
    }
    {
        GemmP p{hp_b, nullptr, Wprs_b, b_prs, mpsp, nullptr};
        gemm_k<128, 64, 0, false><<<dim3(T * B / 128, 2 * STATE / 64, 1), BDIM, 0, stream>>>(
            p, p, HIDDEN, 0, HIDDEN, T * B, 2 * STATE);
    }
    head_pw<<<(T * B * STATE) / BDIM, BDIM, 0, stream>>>(
        mpsp, eps_p, o_prs, o_prm, o_prsd, T * B * STATE);
}

// Round 4
// 2155.638 us; speedup vs baseline: 2.5534x; 2.5534x over previous
//
#include <hip/hip_runtime.h>
#include <hip/hip_bf16.h>
#include <cstdint>

typedef __attribute__((ext_vector_type(4))) float f32x4;
typedef __attribute__((ext_vector_type(8))) short s16x8;
typedef __hip_bfloat16 bf;

#define BDIM 256

// ---------------------------------------------------------------------------
// Coherent (IC-routed, L2-bypass) helpers: relaxed agent-scope atomics compile
// to sc1 global ops -> write-through / bypass, always coherent across XCDs,
// NO buffer_wbl2 / buffer_inv fences needed.
// ---------------------------------------------------------------------------
__device__ __forceinline__ unsigned long long ld_a64(const bf* p) {
    return __hip_atomic_load((const unsigned long long*)p, __ATOMIC_RELAXED,
                             __HIP_MEMORY_SCOPE_AGENT);
}
__device__ __forceinline__ float ld_af(const float* p) {
    return __hip_atomic_load(p, __ATOMIC_RELAXED, __HIP_MEMORY_SCOPE_AGENT);
}
__device__ __forceinline__ void st_au(unsigned* p, unsigned v) {
    __hip_atomic_store(p, v, __ATOMIC_RELAXED, __HIP_MEMORY_SCOPE_AGENT);
}
__device__ __forceinline__ void st_af(float* p, float v) {
    __hip_atomic_store(p, v, __ATOMIC_RELAXED, __HIP_MEMORY_SCOPE_AGENT);
}
// Pack (col,col+1) bf16 from lane pair, even lane stores one dword (sc1).
__device__ __forceinline__ void st_bf_pair(bf* base, size_t off_even, float v, int lane) {
    float v2 = __shfl_xor(v, 1);
    bf lo = __float2bfloat16(v), hi = __float2bfloat16(v2);
    if (!(lane & 1)) {
        unsigned pk = (unsigned)*(unsigned short*)&lo |
                      ((unsigned)*(unsigned short*)&hi << 16);
        st_au((unsigned*)(base + off_even), pk);
    }
}

// ---------------------------------------------------------------------------
// Generic bf16 MFMA gemm (batched pre/post work only).
// ---------------------------------------------------------------------------
struct GemmP {
    const bf* A1;
    const bf* A2;
    const bf* W;
    const float* bias;
    float* outF;
    bf* outB;
};

template <int BM, int BN, int ACT, bool OUTB>
__global__ __launch_bounds__(BDIM) void gemm_k(GemmP p0, GemmP p1, int K1, int K2, int ldw,
                                               int M, int N) {
    constexpr int LDT = 40;
    __shared__ short lA[BM * LDT];
    __shared__ short lW[BN * LDT];
    const GemmP p = (blockIdx.z == 0) ? p0 : p1;
    const int K = K1 + K2;
    const int bm = blockIdx.x * BM;
    const int bn = blockIdx.y * BN;
    const int tid = threadIdx.x;
    const int lane = tid & 63;
    const int wid = tid >> 6;
    constexpr int WM = BM / 2, WN = BN / 2;
    constexpr int TM = WM / 16, TN = WN / 16;
    const int wm = (wid >> 1) * WM;
    const int wn = (wid & 1) * WN;
    const int q = lane >> 4, l16 = lane & 15;
    (void)M;

    f32x4 acc[TM][TN] = {};

    for (int k0 = 0; k0 < K; k0 += 32) {
        for (int c = tid; c < BM * 4; c += BDIM) {
            int row = c >> 2, kc = c & 3;
            int k = k0 + kc * 8;
            const bf* src;
            if (k < K1) src = p.A1 + (size_t)(bm + row) * K1 + k;
            else        src = p.A2 + (size_t)(bm + row) * K2 + (k - K1);
            *(s16x8*)(lA + row * LDT + kc * 8) = *(const s16x8*)src;
        }
        for (int c = tid; c < BN * 4; c += BDIM) {
            int row = c >> 2, kc = c & 3;
            int k = k0 + kc * 8;
            *(s16x8*)(lW + row * LDT + kc * 8) =
                *(const s16x8*)(p.W + (size_t)(bn + row) * ldw + k);
        }
        __syncthreads();

        s16x8 af[TM], wf[TN];
#pragma unroll
        for (int i = 0; i < TM; i++)
            af[i] = *(const s16x8*)(lA + (wm + i * 16 + l16) * LDT + q * 8);
#pragma unroll
        for (int j = 0; j < TN; j++)
            wf[j] = *(const s16x8*)(lW + (wn + j * 16 + l16) * LDT + q * 8);
#pragma unroll
        for (int i = 0; i < TM; i++)
#pragma unroll
            for (int j = 0; j < TN; j++)
                acc[i][j] = __builtin_amdgcn_mfma_f32_16x16x32_bf16(af[i], wf[j], acc[i][j], 0, 0, 0);
        __syncthreads();
    }

#pragma unroll
    for (int i = 0; i < TM; i++)
#pragma unroll
        for (int j = 0; j < TN; j++)
#pragma unroll
            for (int r = 0; r < 4; r++) {
                int row = bm + wm + i * 16 + q * 4 + r;
                int col = bn + wn + j * 16 + l16;
                float v = acc[i][j][r] + p.bias[col];
                if (ACT == 1) v = v > 0.0f ? v : expm1f(v);
                if (OUTB) p.outB[(size_t)row * N + col] = __float2bfloat16(v);
                else      p.outF[(size_t)row * N + col] = v;
            }
}

// ---------------------------------------------------------------------------
// Persistent-scan GEMM tile: BK=64, LDS-staged, 3-buffer register prefetch
// ring, XOR-swizzled LDS (conflict-free, proven r2). CA=true: A1 loaded via
// sc1 (coherent) 8B atomic loads; W / A2 use normal cached loads (weights
// stay hot in per-XCD L2 now that no fences invalidate it).
// ---------------------------------------------------------------------------
template <int BM, int BN, int WR, int WC, bool CA>
__device__ __forceinline__ void gemm_tile(
    const bf* __restrict__ A1, int lda1, int K1,
    const bf* __restrict__ A2, int lda2, int K2,
    const bf* __restrict__ W, int ldw, int wrow0, int gstride,
    int arow0, short* lA, short* lW,
    f32x4 (&acc)[BM / (16 * WR)][BN / (16 * WC)]) {
    constexpr int TM = BM / (16 * WR), TN = BN / (16 * WC);
    constexpr int ACH = (BM * 8) / BDIM;
    constexpr int WCH = (BN * 8 + BDIM - 1) / BDIM;
    constexpr bool WFULL = (BN * 8) % BDIM == 0;
    const int tid = threadIdx.x;
    const int lane = tid & 63, wid = tid >> 6;
    const int wm = (wid / WC) * (BM / WR);
    const int wn = (wid % WC) * (BN / WC);
    const int q = lane >> 4, l16 = lane & 15;
    const int K = K1 + K2;
    const int niter = (K + 63) >> 6;

    s16x8 raA[ACH], rwA[WCH], raB[ACH], rwB[WCH], raC[ACH], rwC[WCH];

    auto issue = [&](s16x8 (&ra)[ACH], s16x8 (&rw)[WCH], int it2) {
        const int k0 = it2 << 6;
#pragma unroll
        for (int uu = 0; uu < ACH; uu++) {
            const int c = tid + uu * BDIM;
            const int row = c >> 3, kc = c & 7;
            const int k = k0 + kc * 8;
            s16x8 v = {};
            if (k < K1) {
                const bf* p = A1 + (size_t)(arow0 + row) * lda1 + k;
                if constexpr (CA) {
                    union { unsigned long long u2[2]; s16x8 s; } t2;
                    t2.u2[0] = ld_a64(p);
                    t2.u2[1] = ld_a64(p + 4);
                    v = t2.s;
                } else {
                    v = *(const s16x8*)p;
                }
            } else if (k < K) {
                v = *(const s16x8*)(A2 + (size_t)(arow0 + row) * lda2 + (k - K1));
            }
            ra[uu] = v;
        }
#pragma unroll
        for (int uu = 0; uu < WCH; uu++) {
            const int c = tid + uu * BDIM;
            if (WFULL || c < BN * 8) {
                const int row = c >> 3, kc = c & 7;
                const int wrr = wrow0 + (row >> 4) * gstride + (row & 15);
                const int k = k0 + kc * 8;
                s16x8 v = {};
                if (k < K) v = *(const s16x8*)(W + (size_t)wrr * ldw + k);
                rw[uu] = v;
            }
        }
    };
    auto commit = [&](const s16x8 (&ra)[ACH], const s16x8 (&rw)[WCH]) {
#pragma unroll
        for (int uu = 0; uu < ACH; uu++) {
            const int c = tid + uu * BDIM;
            const int row = c >> 3, kc = c & 7;
            *(s16x8*)(lA + row * 64 + ((kc ^ (row & 7)) << 3)) = ra[uu];
        }
#pragma unroll
        for (int uu = 0; uu < WCH; uu++) {
            const int c = tid + uu * BDIM;
            if (WFULL || c < BN * 8) {
                const int row = c >> 3, kc = c & 7;
                *(s16x8*)(lW + row * 64 + ((kc ^ (row & 7)) << 3)) = rw[uu];
            }
        }
    };
    auto compute = [&]() {
#pragma unroll
        for (int kk = 0; kk < 2; kk++) {
            const int ch = kk * 4 + q;
            s16x8 af[TM], wf[TN];
#pragma unroll
            for (int i = 0; i < TM; i++) {
                const int r = wm + i * 16 + l16;
                af[i] = *(const s16x8*)(lA + r * 64 + ((ch ^ (r & 7)) << 3));
            }
#pragma unroll
            for (int j = 0; j < TN; j++) {
                const int r = wn + j * 16 + l16;
                wf[j] = *(const s16x8*)(lW + r * 64 + ((ch ^ (r & 7)) << 3));
            }
#pragma unroll
            for (int i = 0; i < TM; i++)
#pragma unroll
                for (int j = 0; j < TN; j++)
                    acc[i][j] = __builtin_amdgcn_mfma_f32_16x16x32_bf16(af[i], wf[j], acc[i][j], 0, 0, 0);
        }
    };

    issue(raA, rwA, 0);
    issue(raB, rwB, 1);
    int it = 0;
    while (true) {
        __syncthreads();
        commit(raA, rwA);
        if (it + 2 < niter) issue(raC, rwC, it + 2);
        __syncthreads();
        compute();
        if (++it >= niter) break;
        __syncthreads();
        commit(raB, rwB);
        if (it + 2 < niter) issue(raA, rwA, it + 2);
        __syncthreads();
        compute();
        if (++it >= niter) break;
        __syncthreads();
        commit(raC, rwC);
        if (it + 2 < niter) issue(raB, rwB, it + 2);
        __syncthreads();
        compute();
        if (++it >= niter) break;
    }
}

// ---------------------------------------------------------------------------
// Fence-free hand-offs. All cross-block data moves via sc1 (IC-coherent) ops,
// so signal = vmcnt-drain + relaxed flag store; wait = subset poll. No
// buffer_wbl2 / buffer_inv anywhere -> weights stay cached in per-XCD L2.
// ---------------------------------------------------------------------------
template <typename PF>
__device__ __forceinline__ void waitf(unsigned* flags, int n, PF pidf,
                                      unsigned tq, unsigned tw) {
    if (threadIdx.x < n) {
        const int p = pidf((int)threadIdx.x);
        const unsigned tgt = (p < 64) ? tq : tw;
        while (__hip_atomic_load(flags + p * 32, __ATOMIC_RELAXED, __HIP_MEMORY_SCOPE_AGENT) < tgt)
            __builtin_amdgcn_s_sleep(1);
    }
    __syncthreads();
    asm volatile("" ::: "memory");
}

__device__ __forceinline__ void sigf(unsigned* flags, int blk, unsigned val) {
    asm volatile("s_waitcnt vmcnt(0)" ::: "memory");  // per-wave: drain sc1 stores
    __syncthreads();
    if (threadIdx.x == 0)
        __hip_atomic_store(flags + blk * 32, val, __ATOMIC_RELAXED, __HIP_MEMORY_SCOPE_AGENT);
}

// ---------------------------------------------------------------------------
// Persistent scan kernel (schedule identical to r3; only the memory paths
// changed). Cross-block buffers: x_b,h_b,hq_b,s_b,gh (sc1). Block-local /
// post-kernel: o_bel, hs_b, o_pos/m/sd (normal cached).
// ---------------------------------------------------------------------------
struct ScanP {
    const bf *Wsa, *Wih, *Whh, *Wpoh, *Wpos;
    const float *b_sa, *b_ih, *b_hh, *b_pos;
    const bf* act;
    const float* obsW;
    bf *x_b, *h_b, *hq_b, *s_b, *hs_b;
    float* gh;
    const float *prev_belief, *nonterm, *eps_q;
    float *o_bel, *o_pos, *o_pom, *o_posd;
    unsigned* flags;
};

__global__ __launch_bounds__(BDIM, 1) void scan_k(ScanP P) {
    __shared__ short lA[64 * 64];
    __shared__ short lW[64 * 64];
    const int blk = blockIdx.x;
    const int tid = threadIdx.x;
    const int lane = tid & 63, wid = tid >> 6;
    const int q = lane >> 4, l16 = lane & 15;
    unsigned* F = P.flags;
    const bool isW = blk >= 64;
    const int mg = (blk >> 3) & 3;
    const int mh = ((blk - 64) >> 3) & 3;

    // ---- XCD-aware tile maps (blk->XCD assumed blk&7) ----
    const int xcd = blk & 7;
    const int s2 = blk >> 3;
    const int c0g = (xcd * 8 + (s2 >> 2)) * 16;
    const int bmg = mg * 64;
    const int u_w = blk - 64;
    const int s_w = u_w >> 3;
    const int bn_h = ((u_w & 7) * 6 + (s_w >> 2)) * 64;
    const int bm_h = (s_w & 3) * 64;
    const int s3 = blk >> 3;
    const int bn_q = (xcd * 2 + (s3 >> 2)) * 64;
    const int bm_q = (s3 & 3) * 64;
    const int c0m = xcd * 16;
    const int bm_m = (blk >> 3) * 64;

    auto do_gh = [&]() {
        const int wm = (wid >> 1) * 32, wn = (wid & 1) * 32;
        f32x4 acc[2][2];
#pragma unroll
        for (int i = 0; i < 2; i++)
#pragma unroll
            for (int j = 0; j < 2; j++) {
                const float b = P.b_hh[bn_h + wn + j * 16 + l16];
                acc[i][j] = (f32x4){b, b, b, b};
            }
        gemm_tile<64, 64, 2, 2, true>(P.h_b, 1024, 1024, nullptr, 0, 0,
                                      P.Whh, 1024, bn_h, 16, bm_h, lA, lW, acc);
#pragma unroll
        for (int i = 0; i < 2; i++)
#pragma unroll
            for (int j = 0; j < 2; j++)
#pragma unroll
                for (int r = 0; r < 4; r++)
                    st_af(&P.gh[(size_t)(bm_h + wm + i * 16 + q * 4 + r) * 3072
                                + bn_h + wn + j * 16 + l16], acc[i][j][r]);
    };

    auto do_x = [&](int tt) {
        const int wm = (wid >> 1) * 32, wn = (wid & 1) * 32;
        f32x4 acc[2][2];
#pragma unroll
        for (int i = 0; i < 2; i++)
#pragma unroll
            for (int j = 0; j < 2; j++) {
                const float b = P.b_sa[bn_q + wn + j * 16 + l16];
                acc[i][j] = (f32x4){b, b, b, b};
            }
        gemm_tile<64, 64, 2, 2, true>(P.s_b, 128, 128, P.act + (size_t)tt * 256 * 32, 32, 32,
                                      P.Wsa, 160, bn_q, 16, bm_q, lA, lW, acc);
#pragma unroll
        for (int i = 0; i < 2; i++)
#pragma unroll
            for (int j = 0; j < 2; j++)
#pragma unroll
                for (int r = 0; r < 4; r++) {
                    float v = acc[i][j][r];
                    v = v > 0.f ? v : expm1f(v);
                    const int row = bm_q + wm + i * 16 + q * 4 + r;
                    const int col = bn_q + wn + j * 16 + l16;
                    st_bf_pair(P.x_b, (size_t)row * 1024 + (col & ~1), v, lane);
                }
    };

    auto do_hq = [&](f32x4 (&acc)[2][2]) {
        const int wm = (wid >> 1) * 32, wn = (wid & 1) * 32;
        gemm_tile<64, 64, 2, 2, true>(P.h_b, 1024, 1024, nullptr, 0, 0,
                                      P.Wpoh, 2048, bn_q, 16, bm_q, lA, lW, acc);
#pragma unroll
        for (int i = 0; i < 2; i++)
#pragma unroll
            for (int j = 0; j < 2; j++)
#pragma unroll
                for (int r = 0; r < 4; r++) {
                    float v = acc[i][j][r];
                    v = v > 0.f ? v : expm1f(v);
                    const int row = bm_q + wm + i * 16 + q * 4 + r;
                    const int col = bn_q + wn + j * 16 + l16;
                    st_bf_pair(P.hq_b, (size_t)row * 1024 + (col & ~1), v, lane);
                }
    };

    auto do_mq = [&](int tt) {
        f32x4 acc[1][2];
#pragma unroll
        for (int j = 0; j < 2; j++) {
            const float b = P.b_pos[j * 128 + c0m + l16];
            acc[0][j] = (f32x4){b, b, b, b};
        }
        gemm_tile<64, 32, 4, 1, true>(P.hq_b, 1024, 1024, nullptr, 0, 0,
                                      P.Wpos, 1024, c0m, 128, bm_m, lA, lW, acc);
        const float* nt1 = (tt + 1 < 50) ? (P.nonterm + (size_t)(tt + 1) * 256) : nullptr;
#pragma unroll
        for (int r = 0; r < 4; r++) {
            const int row = bm_m + wid * 16 + q * 4 + r;
            const int col = c0m + l16;
            const size_t oi = (size_t)tt * 32768 + (size_t)row * 128 + col;
            const float m = acc[0][0][r], sraw = acc[0][1][r];
            const float s = (sraw > 20.f ? sraw : log1pf(expf(sraw))) + 0.1f;
            const float st = m + s * P.eps_q[oi];
            P.o_pom[oi] = m;
            P.o_posd[oi] = s;
            P.o_pos[oi] = st;
            if (nt1) st_bf_pair(P.s_b, (size_t)row * 128 + (col & ~1), st * nt1[row], lane);
        }
    };

    // ---- prologue: x(0) || gh(0) ----
    if (isW) { do_gh(); sigf(F, blk, 1); }
    else     { do_x(0); sigf(F, blk, 1); }

    for (int t = 0; t < 50; t++) {
        const unsigned q0 = 1 + 4u * (unsigned)t, w0 = 1 + 2u * (unsigned)t;

        // ---- gi(t): GEMM needs x rows bmg (16 Q producers); epilogue needs
        //      gh rows bmg (48 W producers, wait overlapped by the GEMM) ----
        {
            f32x4 acc[1][3];
#pragma unroll
            for (int g = 0; g < 3; g++) {
                const float b = P.b_ih[g * 1024 + c0g + l16];
                acc[0][g] = (f32x4){b, b, b, b};
            }
            waitf(F, 16, [&](int i) { return ((i >> 3) << 5) | (mg << 3) | (i & 7); }, q0, 0u);
            gemm_tile<64, 48, 4, 1, true>(P.x_b, 1024, 1024, nullptr, 0, 0,
                                          P.Wih, 1024, c0g, 1024, bmg, lA, lW, acc);
            waitf(F, 48, [&](int i) { return 64 + (((i >> 3) << 5) | (mg << 3) | (i & 7)); }, 0u, w0);
            const float* bel = (t == 0) ? P.prev_belief : (P.o_bel + (size_t)(t - 1) * 262144);
#pragma unroll
            for (int r = 0; r < 4; r++) {
                const int row = bmg + wid * 16 + q * 4 + r;
                const int col = c0g + l16;
                const size_t o3 = (size_t)row * 3072 + col;
                const float gir = acc[0][0][r] + ld_af(&P.gh[o3]);
                const float giz = acc[0][1][r] + ld_af(&P.gh[o3 + 1024]);
                const float rr = 1.f / (1.f + expf(-gir));
                const float zz = 1.f / (1.f + expf(-giz));
                const float nn = tanhf(acc[0][2][r] + rr * ld_af(&P.gh[o3 + 2048]));
                const size_t oo = (size_t)row * 1024 + col;
                const float h = (1.f - zz) * nn + zz * bel[oo];
                P.o_bel[(size_t)t * 262144 + oo] = h;          // block-local + output
                P.hs_b[(size_t)t * 262144 + oo] = __float2bfloat16(h);  // post-scan
                st_bf_pair(P.h_b, (size_t)row * 1024 + (col & ~1), h, lane);  // cross-block
            }
        }
        sigf(F, blk, isW ? w0 + 1 : q0 + 1);

        if (isW) {
            if (t == 49) break;
            waitf(F, 64, [&](int i) { return ((i >> 3) << 5) | (mh << 3) | (i & 7); },
                  q0 + 1, w0 + 1);
            do_gh();
            sigf(F, blk, w0 + 2);
        } else {
            f32x4 qa[2][2];
            const int wm = (wid >> 1) * 32, wn = (wid & 1) * 32;
#pragma unroll
            for (int i = 0; i < 2; i++)
#pragma unroll
                for (int j = 0; j < 2; j++)
#pragma unroll
                    for (int r = 0; r < 4; r++)
                        qa[i][j][r] = P.obsW[(size_t)(t * 256 + bm_q + wm + i * 16 + q * 4 + r) * 1024
                                             + bn_q + wn + j * 16 + l16];
            waitf(F, 64, [&](int i) { return ((i >> 3) << 5) | (mg << 3) | (i & 7); },
                  q0 + 1, w0 + 1);
            do_hq(qa);
            sigf(F, blk, blk < 32 ? q0 + 2 : q0 + 3);
            if (blk < 32) {
                waitf(F, 16, [&](int i) { return ((i >> 3) << 5) | (mg << 3) | (i & 7); },
                      q0 + 2, 0u);
                do_mq(t);
                sigf(F, blk, q0 + 3);
            }
            if (t == 49) break;
            waitf(F, 8, [&](int i) { return (mg << 3) | i; }, q0 + 3, 0u);
            do_x(t + 1);
            sigf(F, blk, q0 + 4);
        }
    }
}

// ---------------------------------------------------------------------------
// Head pointwise for batched prior outputs.
// ---------------------------------------------------------------------------
__global__ __launch_bounds__(BDIM) void head_pw(const float* __restrict__ msq, const float* __restrict__ eps,
                                                float* __restrict__ o_st, float* __restrict__ o_mu,
                                                float* __restrict__ o_sd, int total) {
    int idx = blockIdx.x * BDIM + threadIdx.x;
    if (idx >= total) return;
    int b = idx >> 7, j = idx & 127;
    float m = msq[(size_t)b * 256 + j];
    float sraw = msq[(size_t)b * 256 + 128 + j];
    float s = (sraw > 20.0f ? sraw : log1pf(expf(sraw))) + 0.1f;
    o_mu[idx] = m;
    o_sd[idx] = s;
    o_st[idx] = m + s * eps[idx];
}

// ---------------------------------------------------------------------------
// Init: s_b = bf16(prev_state * nt[0]), h_b = bf16(prev_belief), zero flags.
// ---------------------------------------------------------------------------
__global__ __launch_bounds__(BDIM) void init_k(const float* __restrict__ prev_state,
                                               const float* __restrict__ nt0,
                                               const float* __restrict__ prev_belief,
                                               bf* __restrict__ s_b,
                                               bf* __restrict__ bel_b,
                                               unsigned* __restrict__ flags) {
    int idx = blockIdx.x * BDIM + threadIdx.x;
    if (idx < 256 * 1024) bel_b[idx] = __float2bfloat16(prev_belief[idx]);
    if (idx < 256 * 128) {
        int b = idx >> 7;
        s_b[idx] = __float2bfloat16(prev_state[idx] * nt0[b]);
    }
    if (idx < 256 * 32) flags[idx] = 0u;
}

// ---------------------------------------------------------------------------
// fp32 -> bf16 conversion of 9 arrays in one launch
// ---------------------------------------------------------------------------
struct ConvP {
    const float* src[9];
    bf* dst[9];
    int n4[9];
};

__global__ __launch_bounds__(BDIM) void conv_k(ConvP cp) {
    int stride = gridDim.x * BDIM;
    int g = blockIdx.x * BDIM + threadIdx.x;
    for (int s = 0; s < 9; s++) {
        const float4* src = (const float4*)cp.src[s];
        unsigned short* dst = (unsigned short*)cp.dst[s];
        int n4 = cp.n4[s];
        for (int i = g; i < n4; i += stride) {
            float4 v = src[i];
            bf h0 = __float2bfloat16(v.x), h1 = __float2bfloat16(v.y);
            bf h2 = __float2bfloat16(v.z), h3 = __float2bfloat16(v.w);
            ushort4 o;
            o.x = *(unsigned short*)&h0;
            o.y = *(unsigned short*)&h1;
            o.z = *(unsigned short*)&h2;
            o.w = *(unsigned short*)&h3;
            *(ushort4*)(dst + (size_t)4 * i) = o;
        }
    }
}

// ---------------------------------------------------------------------------
extern "C" void kernel_launch(void* const* d_in, const int* in_sizes, int n_in,
                              void* d_out, int out_size, void* d_ws, size_t ws_size,
                              hipStream_t stream) {
    constexpr int B = 256, T = 50;
    constexpr int BELIEF = 1024, STATE = 128, ACTION = 32, HIDDEN = 1024, EMBED = 1024;

    const float* prev_state  = (const float*)d_in[0];
    const float* actions     = (const float*)d_in[1];
    const float* prev_belief = (const float*)d_in[2];
    const float* observ      = (const float*)d_in[3];
    const float* nonterm     = (const float*)d_in[4];
    const float* eps_p       = (const float*)d_in[5];
    const float* eps_q       = (const float*)d_in[6];
    const float* W_sa  = (const float*)d_in[7];
    const float* b_sa  = (const float*)d_in[8];
    const float* W_ih  = (const float*)d_in[9];
    const float* b_ih  = (const float*)d_in[10];
    const float* W_hh  = (const float*)d_in[11];
    const float* b_hh  = (const float*)d_in[12];
    const float* W_prh = (const float*)d_in[13];
    const float* b_prh = (const float*)d_in[14];
    const float* W_prs = (const float*)d_in[15];
    const float* b_prs = (const float*)d_in[16];
    const float* W_poh = (const float*)d_in[17];
    const float* b_poh = (const float*)d_in[18];
    const float* W_pos = (const float*)d_in[19];
    const float* b_pos = (const float*)d_in[20];
    float* out = (float*)d_out;

    // ---- workspace carve ----
    char* wsp = (char*)d_ws;
    size_t off = 0;
    auto alloc = [&](size_t bytes) -> void* {
        void* p = wsp + off;
        off = (off + bytes + 255) & ~(size_t)255;
        return p;
    };
    bf* Wsa_b  = (bf*)alloc((size_t)BELIEF * (STATE + ACTION) * 2);
    bf* Wih_b  = (bf*)alloc((size_t)3 * BELIEF * BELIEF * 2);
    bf* Whh_b  = (bf*)alloc((size_t)3 * BELIEF * BELIEF * 2);
    bf* Wprh_b = (bf*)alloc((size_t)HIDDEN * BELIEF * 2);
    bf* Wprs_b = (bf*)alloc((size_t)2 * STATE * HIDDEN * 2);
    bf* Wpoh_b = (bf*)alloc((size_t)HIDDEN * (BELIEF + EMBED) * 2);
    bf* Wpos_b = (bf*)alloc((size_t)2 * STATE * HIDDEN * 2);
    bf* act_b  = (bf*)alloc((size_t)T * B * ACTION * 2);
    bf* s_b    = (bf*)alloc((size_t)B * STATE * 2);
    bf* x_b    = (bf*)alloc((size_t)B * BELIEF * 2);
    bf* h_b    = (bf*)alloc((size_t)B * BELIEF * 2);
    bf* hq_b   = (bf*)alloc((size_t)B * HIDDEN * 2);
    bf* hs_b   = (bf*)alloc((size_t)T * B * BELIEF * 2);
    float* gh_ws = (float*)alloc((size_t)B * 3 * BELIEF * 4);
    unsigned* flags = (unsigned*)alloc(256 * 32 * 4);
    bf* obs_b  = (bf*)alloc((size_t)T * B * EMBED * 2);            // dead after obsW gemm
    float* obsW = (float*)alloc((size_t)T * B * HIDDEN * 4);       // dead after scan
    bf* hp_b    = obs_b;                                           // post-scan alias
    float* mpsp = obsW;                                            // post-scan alias
    (void)ws_size; (void)in_sizes; (void)n_in; (void)out_size;

    // ---- output layout ----
    const size_t BEL = (size_t)T * B * BELIEF;
    const size_t SML = (size_t)T * B * STATE;
    float* o_bel  = out;
    float* o_prs  = out + BEL;
    float* o_prm  = o_prs + SML;
    float* o_prsd = o_prm + SML;
    float* o_pos  = o_prsd + SML;
    float* o_pom  = o_pos + SML;
    float* o_posd = o_pom + SML;

    // ---- one-time conversions ----
    ConvP cp;
    cp.src[0] = W_sa;   cp.dst[0] = Wsa_b;  cp.n4[0] = BELIEF * (STATE + ACTION) / 4;
    cp.src[1] = W_ih;   cp.dst[1] = Wih_b;  cp.n4[1] = 3 * BELIEF * BELIEF / 4;
    cp.src[2] = W_hh;   cp.dst[2] = Whh_b;  cp.n4[2] = 3 * BELIEF * BELIEF / 4;
    cp.src[3] = W_prh;  cp.dst[3] = Wprh_b; cp.n4[3] = HIDDEN * BELIEF / 4;
    cp.src[4] = W_prs;  cp.dst[4] = Wprs_b; cp.n4[4] = 2 * STATE * HIDDEN / 4;
    cp.src[5] = W_poh;  cp.dst[5] = Wpoh_b; cp.n4[5] = HIDDEN * (BELIEF + EMBED) / 4;
    cp.src[6] = W_pos;  cp.dst[6] = Wpos_b; cp.n4[6] = 2 * STATE * HIDDEN / 4;
    cp.src[7] = actions; cp.dst[7] = act_b; cp.n4[7] = T * B * ACTION / 4;
    cp.src[8] = observ;  cp.dst[8] = obs_b; cp.n4[8] = T * B * EMBED / 4;
    conv_k<<<2048, BDIM, 0, stream>>>(cp);
    init_k<<<(B * BELIEF) / BDIM, BDIM, 0, stream>>>(prev_state, nonterm, prev_belief, s_b, h_b, flags);

    // ---- precompute obsW[t] = obs_t @ Wpoh_obs^T + b_poh (batched over T) ----
    {
        GemmP p{obs_b, nullptr, Wpoh_b + EMBED, b_poh, obsW, nullptr};
        gemm_k<128, 64, 0, false><<<dim3(T * B / 128, HIDDEN / 64, 1), BDIM, 0, stream>>>(
            p, p, EMBED, 0, BELIEF + EMBED, T * B, HIDDEN);
    }

    // ---- persistent scan: all 50 timesteps in one kernel ----
    {
        ScanP SP;
        SP.Wsa = Wsa_b; SP.Wih = Wih_b; SP.Whh = Whh_b; SP.Wpoh = Wpoh_b; SP.Wpos = Wpos_b;
        SP.b_sa = b_sa; SP.b_ih = b_ih; SP.b_hh = b_hh; SP.b_pos = b_pos;
        SP.act = act_b; SP.obsW = obsW;
        SP.x_b = x_b; SP.h_b = h_b; SP.hq_b = hq_b; SP.s_b = s_b; SP.hs_b = hs_b;
        SP.gh = gh_ws;
        SP.prev_belief = prev_belief; SP.nonterm = nonterm; SP.eps_q = eps_q;
        SP.o_bel = o_bel; SP.o_pos = o_pos; SP.o_pom = o_pom; SP.o_posd = o_posd;
        SP.flags = flags;
        scan_k<<<256, BDIM, 0, stream>>>(SP);
    }

    // ---- prior head, batched over all T (off the critical path) ----
    {
        GemmP p{hs_b, nullptr, Wprh_b, b_prh, nullptr, hp_b};
        gemm_k<128, 64, 1, true><<<dim3(T * B / 128, HIDDEN / 64, 1), BDIM, 0, stream>>>(
            p, p, BELIEF, 0, BELIEF, T * B, HIDDEN);
    }
    {
        GemmP p{hp_b, nullptr, Wprs_b, b_prs, mpsp, nullptr};
        gemm_k<128, 64, 0, false><<<dim3(T * B / 128, 2 * STATE / 64, 1), BDIM, 0, stream>>>(
            p, p, HIDDEN, 0, HIDDEN, T * B, 2 * STATE);
    }
    head_pw<<<(T * B * STATE) / BDIM, BDIM, 0, stream>>>(
        mpsp, eps_p, o_prs, o_prm, o_prsd, T * B * STATE);
}